// Round 3
// baseline (179.819 us; speedup 1.0000x reference)
//
#include <hip/hip_runtime.h>
#include <stdint.h>

#define BATCH 8
#define HIN   28
#define CH    32
#define HO    14
#define NIN   784   // 28*28
#define NOUT  196   // 14*14

// Kernel A: one thread per (b, output-window p).
// Per channel: max over the 2x2 window -> mu_out; argmax k (dy*2+dx, first-match
// ties via strict >, TF order). Pack k (2 bits/channel) into one uint64 per
// (b,p) -> kpack (1568 * 8B = 12.5 KB in d_ws, L1/L2-resident for kernel B).
__global__ void pool_argmax_kernel(const float* __restrict__ mu_in,
                                   float* __restrict__ mu_out,
                                   unsigned long long* __restrict__ kpack) {
    int t = blockIdx.x * blockDim.x + threadIdx.x;
    if (t >= BATCH * NOUT) return;
    int b  = t / NOUT;
    int p  = t - b * NOUT;
    int py = p / HO;
    int px = p - py * HO;
    int iy0 = py * 2, ix0 = px * 2;
    const float* base = mu_in + (((size_t)b * HIN + iy0) * HIN + ix0) * CH;
    float* outp = mu_out + (size_t)t * CH;

    unsigned long long kp = 0ull;
    #pragma unroll
    for (int c = 0; c < CH; ++c) {
        float v0 = base[c];                 // (dy=0,dx=0)
        float v1 = base[CH + c];            // (dy=0,dx=1)
        float v2 = base[HIN * CH + c];      // (dy=1,dx=0)
        float v3 = base[HIN * CH + CH + c]; // (dy=1,dx=1)
        float best = v0; int k = 0;
        if (v1 > best) { best = v1; k = 1; }   // strict > keeps first max
        if (v2 > best) { best = v2; k = 2; }
        if (v3 > best) { best = v3; k = 3; }
        outp[c] = best;
        kp |= (unsigned long long)k << (2 * c);
    }
    kpack[t] = kp;
}

// Kernel B: dense-stream gather with 64B-granular skips.
// Thread = (b,p,q,half). Its 16 channels' values live in 16 candidate pieces:
// piece pc = (di,dj), di/dj in [0,4) over the 2x2 i- and j-windows; each piece
// is 64B (16 contiguous channel floats at exact (i,j)). Load a piece only if
// some channel selects it (presence bitmap from packed argmax codes):
// E[pieces] = 16*(1-(15/16)^16) ~ 10.3 -> ~64% of the input streamed, as
// contiguous 64B chunks. half is interleaved in tid so lane pairs cover
// adjacent 64B halves -> dense wave-level streams. Output row written
// fully coalesced (128B per lane pair).
__global__ __launch_bounds__(256) void sigma_gather_kernel(
        const float* __restrict__ sigma_in,
        const unsigned long long* __restrict__ kpack,
        float* __restrict__ sigma_out) {
    uint32_t t = blockIdx.x * 256u + threadIdx.x;
    const uint32_t TOT = (uint32_t)BATCH * NOUT * NOUT * 2u;  // 614,656
    if (t >= TOT) return;

    uint32_t half = t & 1u;        // which 16-channel half
    uint32_t r    = t >> 1;        // (b*NOUT + p)*NOUT + q
    uint32_t q  = r % NOUT;
    uint32_t bp = r / NOUT;
    uint32_t p  = bp % NOUT;
    uint32_t b  = bp / NOUT;

    uint32_t kph = (uint32_t)(kpack[bp]           >> (32u * half));
    uint32_t kqh = (uint32_t)(kpack[b * NOUT + q] >> (32u * half));

    // per-channel piece index + presence bitmap over the 16 pieces
    uint32_t idxsel[16];
    uint32_t pres = 0u;
    #pragma unroll
    for (int cl = 0; cl < 16; ++cl) {
        uint32_t kp2 = (kph >> (2 * cl)) & 3u;   // i-candidate (dy*2+dx)
        uint32_t kq2 = (kqh >> (2 * cl)) & 3u;   // j-candidate
        idxsel[cl] = (kp2 << 2) | kq2;
        pres |= (1u << idxsel[cl]);
    }

    uint32_t py = p / HO, px = p - py * HO;
    uint32_t qy = q / HO, qx = q - qy * HO;
    uint32_t ibase = (2u * py) * HIN + 2u * px;  // flat i for di=0
    uint32_t jbase = (2u * qy) * HIN + 2u * qx;  // flat j for dj=0

    const float* sb = sigma_in + (size_t)b * NIN * NIN * CH + half * 16u;

    float out[16];
    #pragma unroll
    for (int cl = 0; cl < 16; ++cl) out[cl] = 0.0f;

    #pragma unroll
    for (uint32_t pc = 0; pc < 16; ++pc) {
        if (pres & (1u << pc)) {                 // per-lane exec mask: skipped
            uint32_t di = pc >> 2, dj = pc & 3u; // lanes don't fetch
            uint32_t i = ibase + (di >> 1) * HIN + (di & 1u);
            uint32_t j = jbase + (dj >> 1) * HIN + (dj & 1u);
            const float4* src = (const float4*)(sb + ((size_t)i * NIN + j) * CH);
            float4 v0 = src[0], v1 = src[1], v2 = src[2], v3 = src[3];
            float piece[16] = {v0.x, v0.y, v0.z, v0.w,  v1.x, v1.y, v1.z, v1.w,
                               v2.x, v2.y, v2.z, v2.w,  v3.x, v3.y, v3.z, v3.w};
            #pragma unroll
            for (int cl = 0; cl < 16; ++cl)
                out[cl] = (idxsel[cl] == pc) ? piece[cl] : out[cl];
        }
    }

    float4* o4 = (float4*)(sigma_out + (size_t)r * CH + half * 16u);
    o4[0] = make_float4(out[0],  out[1],  out[2],  out[3]);
    o4[1] = make_float4(out[4],  out[5],  out[6],  out[7]);
    o4[2] = make_float4(out[8],  out[9],  out[10], out[11]);
    o4[3] = make_float4(out[12], out[13], out[14], out[15]);
}

extern "C" void kernel_launch(void* const* d_in, const int* in_sizes, int n_in,
                              void* d_out, int out_size, void* d_ws, size_t ws_size,
                              hipStream_t stream) {
    const float* mu_in    = (const float*)d_in[0];
    const float* sigma_in = (const float*)d_in[1];

    float* mu_out    = (float*)d_out;                      // 8*14*14*32 floats
    float* sigma_out = (float*)d_out + BATCH * NOUT * CH;  // 8*196*196*32 floats

    unsigned long long* kpack = (unsigned long long*)d_ws; // 1568 * 8B

    {
        int total  = BATCH * NOUT;               // 1568
        int block  = 256;
        int blocks = (total + block - 1) / block;
        pool_argmax_kernel<<<blocks, block, 0, stream>>>(mu_in, mu_out, kpack);
    }
    {
        uint32_t TOT = (uint32_t)BATCH * NOUT * NOUT * 2u; // 614,656
        int block    = 256;
        uint32_t blocks = (TOT + block - 1) / block;       // 2401
        sigma_gather_kernel<<<blocks, block, 0, stream>>>(
            sigma_in, kpack, sigma_out);
    }
}